// Round 20
// baseline (217.534 us; speedup 1.0000x reference)
//
#include <hip/hip_runtime.h>

#define EMBED 1024
#define HEADS 16
#define HDIM  64
#define SEQ   2048
#define BATCH 4
#define MTOT  (BATCH*SEQ)

typedef __attribute__((ext_vector_type(8)))  short short8;
typedef __attribute__((ext_vector_type(4)))  float f32x4;
typedef __attribute__((ext_vector_type(16))) float f32x16;

#define GLOAD_LDS16(g, l) \
  __builtin_amdgcn_global_load_lds((const __attribute__((address_space(1))) void*)(g), \
                                   (__attribute__((address_space(3))) void*)(l), 16, 0, 0)

__device__ inline unsigned short f2bf(float f) {
  union { float f; unsigned u; } v; v.f = f;
  unsigned r = v.u + 0x7FFF + ((v.u >> 16) & 1);
  return (unsigned short)(r >> 16);
}

__device__ inline unsigned cvtpk(float lo, float hi) {
  unsigned r;
  asm("v_cvt_pk_bf16_f32 %0, %1, %2" : "=v"(r) : "v"(lo), "v"(hi));
  return r;
}

// raw 2^x — single trans-pipe instr; inputs bounded (|x| < ~8), no edge cases
__device__ inline float vexp2(float x) {
  float r;
  asm("v_exp_f32 %0, %1" : "=v"(r) : "v"(x));
  return r;
}

// v_permlane32_swap_b32 vdst, vsrc — HW semantics (R6/R7 falsification test):
// new vdst[32:63] = old vsrc[0:31]; new vsrc[0:31] = old vdst[32:63].
#define PLSWAP(a, b) asm("v_permlane32_swap_b32 %0, %1" : "+v"(a), "+v"(b))

__device__ inline short8 mk8(unsigned w0, unsigned w1, unsigned w2, unsigned w3) {
  union { unsigned u[4]; short8 s; } x;
  x.u[0] = w0; x.u[1] = w1; x.u[2] = w2; x.u[3] = w3;
  return x.s;
}

// ---------- kernel 2: W [K][N] fp32 -> Wt [N][K] bf16 (x3) ----------
__global__ void transpose_w(const float* __restrict__ Wq, const float* __restrict__ Wk,
                            const float* __restrict__ Wv, unsigned short* __restrict__ Wtb) {
  __shared__ float tile[32][33];
  int wsel = blockIdx.z;
  const float* W = wsel == 0 ? Wq : (wsel == 1 ? Wk : Wv);
  int k0 = blockIdx.x * 32, n0 = blockIdx.y * 32;
  int tx = threadIdx.x & 31, ty = threadIdx.x >> 5;
  for (int i = 0; i < 4; ++i)
    tile[ty + i*8][tx] = W[(k0 + ty + i*8) * EMBED + n0 + tx];
  __syncthreads();
  unsigned short* o = Wtb + wsel * EMBED * EMBED;
  for (int i = 0; i < 4; ++i)
    o[(n0 + ty + i*8) * EMBED + k0 + tx] = f2bf(tile[tx][ty + i*8]);
}

// ---------- kernel 3: QKV projection GEMM (fused x fp32 read + cvt; XCD-chunked grid) ----------
// 1536 blocks 1D; lid = (bid%8)*192 + bid/8 (bijective). lid -> (mi, ni, wsel)
// with (ni,wsel) innermost: each XCD owns 8 consecutive m-panels (4 MB fp32 A)
// x all (n0,wsel) -> A fetched ~once per XCD instead of ~24x.
// Q output pre-scaled by 0.125*log2(e) so attn's softmax needs no per-score FMA.
__global__ __launch_bounds__(256)
void qkv_gemm(const float* __restrict__ x, const unsigned short* __restrict__ Wtb,
              const float* __restrict__ bq, const float* __restrict__ bk, const float* __restrict__ bv,
              unsigned short* __restrict__ Qb, unsigned short* __restrict__ Kb,
              unsigned short* __restrict__ Vt) {
  __shared__ unsigned short As[128 * 72];
  __shared__ unsigned short Bs[128 * 72];
  int lid  = ((blockIdx.x & 7) * 192) + (blockIdx.x >> 3);
  int mi   = lid / 24;
  int rem  = lid % 24;
  int ni   = rem / 3;
  int wsel = rem % 3;
  int m0 = mi * 128, n0 = ni * 128;
  int t = threadIdx.x, lane = t & 63, wave = t >> 6;
  int wr = wave >> 1, wc = wave & 1;
  int lr = lane & 15, lg = lane >> 4;
  const unsigned short* Wt = Wtb + wsel * (EMBED * EMBED);
  const float* bias = wsel == 0 ? bq : (wsel == 1 ? bk : bv);

  f32x4 acc[4][4] = {};

  for (int kt = 0; kt < EMBED / 64; ++kt) {
    int k0 = kt * 64;
    for (int i = 0; i < 4; ++i) {
      int c = i * 256 + t;
      int row = c >> 3, col8 = c & 7;
      const float* xr = x + (m0 + row) * EMBED + k0 + col8 * 8;
      f32x4 a0 = *(const f32x4*)xr;
      f32x4 a1 = *(const f32x4*)(xr + 4);
      unsigned short o[8];
      o[0]=f2bf(a0[0]); o[1]=f2bf(a0[1]); o[2]=f2bf(a0[2]); o[3]=f2bf(a0[3]);
      o[4]=f2bf(a1[0]); o[5]=f2bf(a1[1]); o[6]=f2bf(a1[2]); o[7]=f2bf(a1[3]);
      short8 vb = *(const short8*)(Wt + (n0 + row) * EMBED + k0 + col8 * 8);
      *(short8*)(As + row * 72 + col8 * 8) = *(short8*)o;
      *(short8*)(Bs + row * 72 + col8 * 8) = vb;
    }
    __syncthreads();
    for (int kk = 0; kk < 2; ++kk) {
      short8 af[4], bfr[4];
      for (int mf = 0; mf < 4; ++mf)
        af[mf] = *(const short8*)(As + (wr * 64 + mf * 16 + lr) * 72 + kk * 32 + lg * 8);
      for (int nf = 0; nf < 4; ++nf)
        bfr[nf] = *(const short8*)(Bs + (wc * 64 + nf * 16 + lr) * 72 + kk * 32 + lg * 8);
      for (int mf = 0; mf < 4; ++mf)
        for (int nf = 0; nf < 4; ++nf)
          acc[mf][nf] = __builtin_amdgcn_mfma_f32_16x16x32_bf16(af[mf], bfr[nf], acc[mf][nf], 0, 0, 0);
    }
    __syncthreads();
  }

  const float SCLQ = 0.125f * 1.44269504088896340736f;
  for (int nf = 0; nf < 4; ++nf) {
    int n = n0 + wc * 64 + nf * 16 + lr;
    float bval = bias[n];
    int h = n >> 6, d = n & 63;
    for (int mf = 0; mf < 4; ++mf) {
      for (int r = 0; r < 4; ++r) {
        int m = m0 + wr * 64 + mf * 16 + lg * 4 + r;
        int b = m >> 11, s = m & 2047;
        float oval = acc[mf][nf][r] + bval;
        if (wsel == 0) oval *= SCLQ;   // wave-uniform branch
        unsigned short bfv = f2bf(oval);
        if (wsel == 0)      Qb[((b * HEADS + h) * SEQ + s) * HDIM + d] = bfv;
        else if (wsel == 1) Kb[((b * HEADS + h) * SEQ + s) * HDIM + d] = bfv;
        else                Vt[((b * HEADS + h) * HDIM + d) * SEQ + s] = bfv;
      }
    }
  }
}

// ---------- kernel 4: flash attention, 32x32 MFMA, swapped QK^T ----------
// Exact R16 structure (best measured: 132.5 us): KVBLK=64, triple-buffer,
// T1 XCD swizzle (FETCH 139->25 MB), counted vmcnt(4) + raw s_barrier,
// T5 setprio, PROC16, in-register softmax via cvt_pk + permlane32_swap.
__global__ __launch_bounds__(256)
void attn(const unsigned short* __restrict__ Qb, const unsigned short* __restrict__ Kb,
          const unsigned short* __restrict__ Vt, const float* __restrict__ rel_bias,
          float* __restrict__ out) {
  __shared__ unsigned short KVs[24576];   // K0|K1|K2 | V0|V1|V2, 8 KB per tile
  __shared__ float bias_l[33];
  __shared__ float dld[4][32];
  // T1 swizzle: XCD = bid%8 owns 8 contiguous bh (4 MB K/V = its L2)
  int lid = ((blockIdx.x & 7) << 7) + (blockIdx.x >> 3);
  int bh = lid >> 4;
  int qb = lid & 15;
  int b = bh >> 4, h = bh & 15;
  int t = threadIdx.x, lane = t & 63, wave = t >> 6;
  int l31 = lane & 31, hi = lane >> 5;
  const float LOG2E = 1.44269504088896340736f;
  if (t < 33) bias_l[t] = rel_bias[t * HEADS + h] * LOG2E;

  int qw0 = qb * 128 + wave * 32;                  // this wave's 32 q-rows
  const unsigned short* Qp = Qb + (bh * SEQ + qw0) * HDIM;
  const unsigned short* Kp = Kb + bh * SEQ * HDIM;
  const unsigned short* Vp = Vt + bh * HDIM * SEQ;

  // Q as B-operand fragments: col=q=l31, k(d) = ks*16 + hi*8 + j
  short8 qf[4];
  #pragma unroll
  for (int ks = 0; ks < 4; ++ks)
    qf[ks] = *(const short8*)(Qp + l31 * HDIM + ks * 16 + hi * 8);

  // precomputed per-lane LDS byte offsets, shared by K and V reads:
  // row = rs*32+l31, slot = (ks*2+hi)^(row&7);  off = row*128 + slot*16
  unsigned rbo[2][4];
  #pragma unroll
  for (int rs = 0; rs < 2; ++rs)
    #pragma unroll
    for (int ks = 0; ks < 4; ++ks) {
      int row = rs * 32 + l31;
      rbo[rs][ks] = (unsigned)((row << 7) + ((((ks << 1) | hi) ^ (row & 7)) << 4));
    }
  // byte layout: K buf i at i*8192; V buf i at 24576 + i*8192
  #define LDK(rs, ks, BUF) \
    (*(const short8*)((const char*)KVs + rbo[rs][ks] + (BUF) * 8192))
  #define LDVv(rs, ks, BUF) \
    (*(const short8*)((const char*)KVs + rbo[rs][ks] + 24576 + (BUF) * 8192))

  f32x16 O0 = {}, O1 = {};
  float ls0 = 0.f, ls1 = 0.f;
  int q = qw0 + l31;

  // staging: wave stages rows [wave*16, wave*16+16)
  int srow0 = (wave << 4) + (lane >> 3);
  int sslot = lane & 7;

  #define STAGE(BUF, key0_)                                                          \
    for (int j = 0; j < 2; ++j) {                                                    \
      int srow = srow0 + j * 8;                                                      \
      int cs = sslot ^ (srow & 7);                                                   \
      GLOAD_LDS16(Kp + ((key0_) + srow) * HDIM + cs * 8,                             \
                  (char*)KVs + (BUF) * 8192 + ((((wave << 4) + j * 8) << 6) << 1));  \
      GLOAD_LDS16(Vp + srow * SEQ + (key0_) + cs * 8,                                \
                  (char*)KVs + 24576 + (BUF) * 8192 + ((((wave << 4) + j * 8) << 6) << 1)); \
    }

  #define WAITV4 asm volatile("s_waitcnt vmcnt(4)" ::: "memory");
  #define WAITV0 asm volatile("s_waitcnt vmcnt(0)" ::: "memory");
  #define BAR    __builtin_amdgcn_s_barrier();

  float cbLo, cbHi;

  // softmax + pack + PV for one 32-key subtile held in acc SACC
  #define PROC(SACC, KOFF, BUF)  {                                                   \
    float pv[16];                                                                    \
    int kbase = key0 + (KOFF);                                                       \
    if (kbase >= qw0 + 47) {                                                         \
      _Pragma("unroll") for (int r = 0; r < 16; ++r)                                 \
        pv[r] = vexp2(SACC[r] + cbHi);                                               \
    } else if (kbase <= qw0 - 47) {                                                  \
      _Pragma("unroll") for (int r = 0; r < 16; ++r)                                 \
        pv[r] = vexp2(SACC[r] + cbLo);                                               \
    } else {                                                                         \
      _Pragma("unroll") for (int r = 0; r < 16; ++r) {                               \
        int key = kbase + (r & 3) + 8 * (r >> 2) + 4 * hi;                           \
        int rel = key - q;                                                           \
        rel = rel < -16 ? -16 : (rel > 16 ? 16 : rel);                               \
        pv[r] = vexp2(SACC[r] + bias_l[rel + 16]);                                   \
      }                                                                              \
    }                                                                                \
    ls0 += ((pv[0] + pv[1]) + (pv[2] + pv[3])) + ((pv[4] + pv[5]) + (pv[6] + pv[7]));\
    ls1 += ((pv[8] + pv[9]) + (pv[10] + pv[11])) + ((pv[12] + pv[13]) + (pv[14] + pv[15]));\
    unsigned a0 = cvtpk(pv[0], pv[1]),  a1 = cvtpk(pv[4], pv[5]);   PLSWAP(a0, a1);  \
    unsigned a2 = cvtpk(pv[2], pv[3]),  a3 = cvtpk(pv[6], pv[7]);   PLSWAP(a2, a3);  \
    unsigned b0 = cvtpk(pv[8], pv[9]),  b1 = cvtpk(pv[12], pv[13]); PLSWAP(b0, b1);  \
    unsigned b2 = cvtpk(pv[10], pv[11]), b3 = cvtpk(pv[14], pv[15]); PLSWAP(b2, b3); \
    short8 pa0 = mk8(a0, a2, a1, a3);                                                \
    short8 pa1 = mk8(b0, b2, b1, b3);                                                \
    __builtin_amdgcn_s_setprio(1);                                                   \
    O0 = __builtin_amdgcn_mfma_f32_32x32x16_bf16(pa0, LDVv(0, (KOFF)/16, BUF),     O0, 0, 0, 0); \
    O1 = __builtin_amdgcn_mfma_f32_32x32x16_bf16(pa0, LDVv(1, (KOFF)/16, BUF),     O1, 0, 0, 0); \
    O0 = __builtin_amdgcn_mfma_f32_32x32x16_bf16(pa1, LDVv(0, (KOFF)/16 + 1, BUF), O0, 0, 0, 0); \
    O1 = __builtin_amdgcn_mfma_f32_32x32x16_bf16(pa1, LDVv(1, (KOFF)/16 + 1, BUF), O1, 0, 0, 0); \
    __builtin_amdgcn_s_setprio(0);                                                   \
  }

  // One 32-key half: QK^T chain then its softmax+PV, as a closed region.
  #define HALF(RS, KOFF, BUF)  {                                                     \
    f32x16 s_ = {};                                                                  \
    __builtin_amdgcn_s_setprio(1);                                                   \
    _Pragma("unroll") for (int ks = 0; ks < 4; ++ks)                                 \
      s_ = __builtin_amdgcn_mfma_f32_32x32x16_bf16(LDK(RS, ks, BUF), qf[ks], s_, 0, 0, 0); \
    __builtin_amdgcn_s_setprio(0);                                                   \
    PROC(s_, KOFF, BUF)                                                              \
  }

  #define COMPUTE(BUF, KEY0)  {                                                      \
    int key0 = (KEY0);                                                               \
    HALF(0, 0, BUF)                                                                  \
    HALF(1, 32, BUF)                                                                 \
  }

  // prologue: stage tiles 0,1; wait tile 0; barrier (also covers bias_l)
  STAGE(0, 0)
  STAGE(1, 64)
  WAITV4
  __syncthreads();
  cbLo = bias_l[0]; cbHi = bias_l[32];

  // main: 30 phases in 10 x3-unrolled iterations; tile kb+2 staged each phase
  for (int i = 0; i < 10; ++i) {
    int t3 = i * 3;
    STAGE(2, (t3 + 2) * 64)  COMPUTE(0, t3 * 64)        WAITV4 BAR
    STAGE(0, (t3 + 3) * 64)  COMPUTE(1, (t3 + 1) * 64)  WAITV4 BAR
    STAGE(1, (t3 + 4) * 64)  COMPUTE(2, (t3 + 2) * 64)  WAITV4 BAR
  }
  // tail: tiles 30, 31 (no more staging; drain)
  COMPUTE(0, 30 * 64)
  WAITV0 BAR
  COMPUTE(1, 31 * 64)

  // ---- epilogue: denom per q, normalize, store ----
  float lsum = ls0 + ls1;
  float denom = lsum + __shfl_xor(lsum, 32, 64);
  if (lane < 32) dld[wave][l31] = 1.0f / denom;   // wave-local, wave-synchronous
  float* op = out + (b * SEQ + qw0) * EMBED + h * HDIM;
  #pragma unroll
  for (int r = 0; r < 16; ++r) {
    int ql = (r & 3) + 8 * (r >> 2) + 4 * hi;
    float inv = dld[wave][ql];
    op[ql * EMBED + l31]      = O0[r] * inv;
    op[ql * EMBED + 32 + l31] = O1[r] * inv;
  }
  #undef STAGE
  #undef LDK
  #undef LDVv
  #undef PROC
  #undef HALF
  #undef COMPUTE
}

extern "C" void kernel_launch(void* const* d_in, const int* in_sizes, int n_in,
                              void* d_out, int out_size, void* d_ws, size_t ws_size,
                              hipStream_t stream) {
  const float* x        = (const float*)d_in[0];
  const float* Wq       = (const float*)d_in[1];
  const float* bq       = (const float*)d_in[2];
  const float* Wk       = (const float*)d_in[3];
  const float* bk       = (const float*)d_in[4];
  const float* Wv       = (const float*)d_in[5];
  const float* bv       = (const float*)d_in[6];
  const float* rel_bias = (const float*)d_in[7];
  float* out = (float*)d_out;

  char* ws = (char*)d_ws;
  unsigned short* Wtb = (unsigned short*)(ws + 16777216);      // 6 MB
  unsigned short* Qb  = (unsigned short*)(ws + 23068672);      // 16 MB
  unsigned short* Kb  = (unsigned short*)(ws + 39845888);      // 16 MB
  unsigned short* Vt  = (unsigned short*)(ws + 56623104);      // 16 MB (total 70 MB)

  transpose_w<<<dim3(32, 32, 3), 256, 0, stream>>>(Wq, Wk, Wv, Wtb);
  qkv_gemm<<<dim3(1536), 256, 0, stream>>>(x, Wtb, bq, bk, bv, Qb, Kb, Vt);
  attn<<<dim3(SEQ / 128 * BATCH * HEADS), 256, 0, stream>>>(Qb, Kb, Vt, rel_bias, out);
}

// Round 21
// 209.589 us; speedup vs baseline: 1.0379x; 1.0379x over previous
//
#include <hip/hip_runtime.h>

#define EMBED 1024
#define HEADS 16
#define HDIM  64
#define SEQ   2048
#define BATCH 4
#define MTOT  (BATCH*SEQ)

typedef __attribute__((ext_vector_type(8)))  short short8;
typedef __attribute__((ext_vector_type(4)))  float f32x4;
typedef __attribute__((ext_vector_type(16))) float f32x16;

#define GLOAD_LDS16(g, l) \
  __builtin_amdgcn_global_load_lds((const __attribute__((address_space(1))) void*)(g), \
                                   (__attribute__((address_space(3))) void*)(l), 16, 0, 0)

__device__ inline unsigned short f2bf(float f) {
  union { float f; unsigned u; } v; v.f = f;
  unsigned r = v.u + 0x7FFF + ((v.u >> 16) & 1);
  return (unsigned short)(r >> 16);
}

__device__ inline unsigned cvtpk(float lo, float hi) {
  unsigned r;
  asm("v_cvt_pk_bf16_f32 %0, %1, %2" : "=v"(r) : "v"(lo), "v"(hi));
  return r;
}

// raw 2^x — single trans-pipe instr; inputs bounded (|x| < ~8), no edge cases
__device__ inline float vexp2(float x) {
  float r;
  asm("v_exp_f32 %0, %1" : "=v"(r) : "v"(x));
  return r;
}

// v_permlane32_swap_b32 vdst, vsrc — HW semantics (R6/R7 falsification test):
// new vdst[32:63] = old vsrc[0:31]; new vsrc[0:31] = old vdst[32:63].
#define PLSWAP(a, b) asm("v_permlane32_swap_b32 %0, %1" : "+v"(a), "+v"(b))

__device__ inline short8 mk8(unsigned w0, unsigned w1, unsigned w2, unsigned w3) {
  union { unsigned u[4]; short8 s; } x;
  x.u[0] = w0; x.u[1] = w1; x.u[2] = w2; x.u[3] = w3;
  return x.s;
}

// ---------- kernel 2: W [K][N] fp32 -> Wt [N][K] bf16 (x3) ----------
__global__ void transpose_w(const float* __restrict__ Wq, const float* __restrict__ Wk,
                            const float* __restrict__ Wv, unsigned short* __restrict__ Wtb) {
  __shared__ float tile[32][33];
  int wsel = blockIdx.z;
  const float* W = wsel == 0 ? Wq : (wsel == 1 ? Wk : Wv);
  int k0 = blockIdx.x * 32, n0 = blockIdx.y * 32;
  int tx = threadIdx.x & 31, ty = threadIdx.x >> 5;
  for (int i = 0; i < 4; ++i)
    tile[ty + i*8][tx] = W[(k0 + ty + i*8) * EMBED + n0 + tx];
  __syncthreads();
  unsigned short* o = Wtb + wsel * EMBED * EMBED;
  for (int i = 0; i < 4; ++i)
    o[(n0 + ty + i*8) * EMBED + k0 + tx] = f2bf(tile[tx][ty + i*8]);
}

// ---------- kernel 3: QKV projection GEMM (x fp32 read + cvt fused in staging) ----------
// 2D grid (mi, ni, wsel): dispatch keeps the live W-slice ~2 MB (L2-resident);
// L3 absorbs A re-reads. R20 showed XCD-chunking W-innermost thrashes L2 (-2.4x).
// Q output is pre-scaled by 0.125*log2(e) so attn's softmax needs no per-score FMA.
__global__ __launch_bounds__(256)
void qkv_gemm(const float* __restrict__ x, const unsigned short* __restrict__ Wtb,
              const float* __restrict__ bq, const float* __restrict__ bk, const float* __restrict__ bv,
              unsigned short* __restrict__ Qb, unsigned short* __restrict__ Kb,
              unsigned short* __restrict__ Vt) {
  __shared__ unsigned short As[128 * 72];
  __shared__ unsigned short Bs[128 * 72];
  int wsel = blockIdx.z;
  int m0 = blockIdx.x * 128, n0 = blockIdx.y * 128;
  int t = threadIdx.x, lane = t & 63, wave = t >> 6;
  int wr = wave >> 1, wc = wave & 1;
  int lr = lane & 15, lg = lane >> 4;
  const unsigned short* Wt = Wtb + wsel * (EMBED * EMBED);
  const float* bias = wsel == 0 ? bq : (wsel == 1 ? bk : bv);

  f32x4 acc[4][4] = {};

  for (int kt = 0; kt < EMBED / 64; ++kt) {
    int k0 = kt * 64;
    for (int i = 0; i < 4; ++i) {
      int c = i * 256 + t;
      int row = c >> 3, col8 = c & 7;
      const float* xr = x + (m0 + row) * EMBED + k0 + col8 * 8;
      f32x4 a0 = *(const f32x4*)xr;
      f32x4 a1 = *(const f32x4*)(xr + 4);
      unsigned short o[8];
      o[0]=f2bf(a0[0]); o[1]=f2bf(a0[1]); o[2]=f2bf(a0[2]); o[3]=f2bf(a0[3]);
      o[4]=f2bf(a1[0]); o[5]=f2bf(a1[1]); o[6]=f2bf(a1[2]); o[7]=f2bf(a1[3]);
      short8 vb = *(const short8*)(Wt + (n0 + row) * EMBED + k0 + col8 * 8);
      *(short8*)(As + row * 72 + col8 * 8) = *(short8*)o;
      *(short8*)(Bs + row * 72 + col8 * 8) = vb;
    }
    __syncthreads();
    for (int kk = 0; kk < 2; ++kk) {
      short8 af[4], bfr[4];
      for (int mf = 0; mf < 4; ++mf)
        af[mf] = *(const short8*)(As + (wr * 64 + mf * 16 + lr) * 72 + kk * 32 + lg * 8);
      for (int nf = 0; nf < 4; ++nf)
        bfr[nf] = *(const short8*)(Bs + (wc * 64 + nf * 16 + lr) * 72 + kk * 32 + lg * 8);
      for (int mf = 0; mf < 4; ++mf)
        for (int nf = 0; nf < 4; ++nf)
          acc[mf][nf] = __builtin_amdgcn_mfma_f32_16x16x32_bf16(af[mf], bfr[nf], acc[mf][nf], 0, 0, 0);
    }
    __syncthreads();
  }

  const float SCLQ = 0.125f * 1.44269504088896340736f;
  for (int nf = 0; nf < 4; ++nf) {
    int n = n0 + wc * 64 + nf * 16 + lr;
    float bval = bias[n];
    int h = n >> 6, d = n & 63;
    for (int mf = 0; mf < 4; ++mf) {
      for (int r = 0; r < 4; ++r) {
        int m = m0 + wr * 64 + mf * 16 + lg * 4 + r;
        int b = m >> 11, s = m & 2047;
        float oval = acc[mf][nf][r] + bval;
        if (wsel == 0) oval *= SCLQ;   // wave-uniform branch
        unsigned short bfv = f2bf(oval);
        if (wsel == 0)      Qb[((b * HEADS + h) * SEQ + s) * HDIM + d] = bfv;
        else if (wsel == 1) Kb[((b * HEADS + h) * SEQ + s) * HDIM + d] = bfv;
        else                Vt[((b * HEADS + h) * HDIM + d) * SEQ + s] = bfv;
      }
    }
  }
}

// ---------- kernel 4: flash attention, 32x32 MFMA, swapped QK^T ----------
// Best-measured structure (R16: 132.5 us): KVBLK=64, triple-buffer, T1 XCD
// swizzle (FETCH 139->25 MB), counted vmcnt(4) + raw s_barrier, T5 setprio,
// PROC16, in-register softmax via cvt_pk + permlane32_swap.
__global__ __launch_bounds__(256)
void attn(const unsigned short* __restrict__ Qb, const unsigned short* __restrict__ Kb,
          const unsigned short* __restrict__ Vt, const float* __restrict__ rel_bias,
          float* __restrict__ out) {
  __shared__ unsigned short KVs[24576];   // K0|K1|K2 | V0|V1|V2, 8 KB per tile
  __shared__ float bias_l[33];
  __shared__ float dld[4][32];
  // T1 swizzle: XCD = bid%8 owns 8 contiguous bh (4 MB K/V = its L2)
  int lid = ((blockIdx.x & 7) << 7) + (blockIdx.x >> 3);
  int bh = lid >> 4;
  int qb = lid & 15;
  int b = bh >> 4, h = bh & 15;
  int t = threadIdx.x, lane = t & 63, wave = t >> 6;
  int l31 = lane & 31, hi = lane >> 5;
  const float LOG2E = 1.44269504088896340736f;
  if (t < 33) bias_l[t] = rel_bias[t * HEADS + h] * LOG2E;

  int qw0 = qb * 128 + wave * 32;                  // this wave's 32 q-rows
  const unsigned short* Qp = Qb + (bh * SEQ + qw0) * HDIM;
  const unsigned short* Kp = Kb + bh * SEQ * HDIM;
  const unsigned short* Vp = Vt + bh * HDIM * SEQ;

  // Q as B-operand fragments: col=q=l31, k(d) = ks*16 + hi*8 + j
  short8 qf[4];
  #pragma unroll
  for (int ks = 0; ks < 4; ++ks)
    qf[ks] = *(const short8*)(Qp + l31 * HDIM + ks * 16 + hi * 8);

  // precomputed per-lane LDS byte offsets, shared by K and V reads:
  // row = rs*32+l31, slot = (ks*2+hi)^(row&7);  off = row*128 + slot*16
  unsigned rbo[2][4];
  #pragma unroll
  for (int rs = 0; rs < 2; ++rs)
    #pragma unroll
    for (int ks = 0; ks < 4; ++ks) {
      int row = rs * 32 + l31;
      rbo[rs][ks] = (unsigned)((row << 7) + ((((ks << 1) | hi) ^ (row & 7)) << 4));
    }
  // byte layout: K buf i at i*8192; V buf i at 24576 + i*8192
  #define LDK(rs, ks, BUF) \
    (*(const short8*)((const char*)KVs + rbo[rs][ks] + (BUF) * 8192))
  #define LDVv(rs, ks, BUF) \
    (*(const short8*)((const char*)KVs + rbo[rs][ks] + 24576 + (BUF) * 8192))

  f32x16 O0 = {}, O1 = {};
  float ls0 = 0.f, ls1 = 0.f;
  int q = qw0 + l31;

  // staging: wave stages rows [wave*16, wave*16+16)
  int srow0 = (wave << 4) + (lane >> 3);
  int sslot = lane & 7;

  #define STAGE(BUF, key0_)                                                          \
    for (int j = 0; j < 2; ++j) {                                                    \
      int srow = srow0 + j * 8;                                                      \
      int cs = sslot ^ (srow & 7);                                                   \
      GLOAD_LDS16(Kp + ((key0_) + srow) * HDIM + cs * 8,                             \
                  (char*)KVs + (BUF) * 8192 + ((((wave << 4) + j * 8) << 6) << 1));  \
      GLOAD_LDS16(Vp + srow * SEQ + (key0_) + cs * 8,                                \
                  (char*)KVs + 24576 + (BUF) * 8192 + ((((wave << 4) + j * 8) << 6) << 1)); \
    }

  #define WAITV4 asm volatile("s_waitcnt vmcnt(4)" ::: "memory");
  #define WAITV0 asm volatile("s_waitcnt vmcnt(0)" ::: "memory");
  #define BAR    __builtin_amdgcn_s_barrier();

  float cbLo, cbHi;

  // softmax + pack + PV for one 32-key subtile held in acc SACC
  #define PROC(SACC, KOFF, BUF)  {                                                   \
    float pv[16];                                                                    \
    int kbase = key0 + (KOFF);                                                       \
    if (kbase >= qw0 + 47) {                                                         \
      _Pragma("unroll") for (int r = 0; r < 16; ++r)                                 \
        pv[r] = vexp2(SACC[r] + cbHi);                                               \
    } else if (kbase <= qw0 - 47) {                                                  \
      _Pragma("unroll") for (int r = 0; r < 16; ++r)                                 \
        pv[r] = vexp2(SACC[r] + cbLo);                                               \
    } else {                                                                         \
      _Pragma("unroll") for (int r = 0; r < 16; ++r) {                               \
        int key = kbase + (r & 3) + 8 * (r >> 2) + 4 * hi;                           \
        int rel = key - q;                                                           \
        rel = rel < -16 ? -16 : (rel > 16 ? 16 : rel);                               \
        pv[r] = vexp2(SACC[r] + bias_l[rel + 16]);                                   \
      }                                                                              \
    }                                                                                \
    ls0 += ((pv[0] + pv[1]) + (pv[2] + pv[3])) + ((pv[4] + pv[5]) + (pv[6] + pv[7]));\
    ls1 += ((pv[8] + pv[9]) + (pv[10] + pv[11])) + ((pv[12] + pv[13]) + (pv[14] + pv[15]));\
    unsigned a0 = cvtpk(pv[0], pv[1]),  a1 = cvtpk(pv[4], pv[5]);   PLSWAP(a0, a1);  \
    unsigned a2 = cvtpk(pv[2], pv[3]),  a3 = cvtpk(pv[6], pv[7]);   PLSWAP(a2, a3);  \
    unsigned b0 = cvtpk(pv[8], pv[9]),  b1 = cvtpk(pv[12], pv[13]); PLSWAP(b0, b1);  \
    unsigned b2 = cvtpk(pv[10], pv[11]), b3 = cvtpk(pv[14], pv[15]); PLSWAP(b2, b3); \
    short8 pa0 = mk8(a0, a2, a1, a3);                                                \
    short8 pa1 = mk8(b0, b2, b1, b3);                                                \
    __builtin_amdgcn_s_setprio(1);                                                   \
    O0 = __builtin_amdgcn_mfma_f32_32x32x16_bf16(pa0, LDVv(0, (KOFF)/16, BUF),     O0, 0, 0, 0); \
    O1 = __builtin_amdgcn_mfma_f32_32x32x16_bf16(pa0, LDVv(1, (KOFF)/16, BUF),     O1, 0, 0, 0); \
    O0 = __builtin_amdgcn_mfma_f32_32x32x16_bf16(pa1, LDVv(0, (KOFF)/16 + 1, BUF), O0, 0, 0, 0); \
    O1 = __builtin_amdgcn_mfma_f32_32x32x16_bf16(pa1, LDVv(1, (KOFF)/16 + 1, BUF), O1, 0, 0, 0); \
    __builtin_amdgcn_s_setprio(0);                                                   \
  }

  // One 32-key half: QK^T chain then its softmax+PV, as a closed region.
  #define HALF(RS, KOFF, BUF)  {                                                     \
    f32x16 s_ = {};                                                                  \
    __builtin_amdgcn_s_setprio(1);                                                   \
    _Pragma("unroll") for (int ks = 0; ks < 4; ++ks)                                 \
      s_ = __builtin_amdgcn_mfma_f32_32x32x16_bf16(LDK(RS, ks, BUF), qf[ks], s_, 0, 0, 0); \
    __builtin_amdgcn_s_setprio(0);                                                   \
    PROC(s_, KOFF, BUF)                                                              \
  }

  #define COMPUTE(BUF, KEY0)  {                                                      \
    int key0 = (KEY0);                                                               \
    HALF(0, 0, BUF)                                                                  \
    HALF(1, 32, BUF)                                                                 \
  }

  // prologue: stage tiles 0,1; wait tile 0; barrier (also covers bias_l)
  STAGE(0, 0)
  STAGE(1, 64)
  WAITV4
  __syncthreads();
  cbLo = bias_l[0]; cbHi = bias_l[32];

  // main: 30 phases in 10 x3-unrolled iterations; tile kb+2 staged each phase
  for (int i = 0; i < 10; ++i) {
    int t3 = i * 3;
    STAGE(2, (t3 + 2) * 64)  COMPUTE(0, t3 * 64)        WAITV4 BAR
    STAGE(0, (t3 + 3) * 64)  COMPUTE(1, (t3 + 1) * 64)  WAITV4 BAR
    STAGE(1, (t3 + 4) * 64)  COMPUTE(2, (t3 + 2) * 64)  WAITV4 BAR
  }
  // tail: tiles 30, 31 (no more staging; drain)
  COMPUTE(0, 30 * 64)
  WAITV0 BAR
  COMPUTE(1, 31 * 64)

  // ---- epilogue: denom per q, normalize, store ----
  float lsum = ls0 + ls1;
  float denom = lsum + __shfl_xor(lsum, 32, 64);
  if (lane < 32) dld[wave][l31] = 1.0f / denom;   // wave-local, wave-synchronous
  float* op = out + (b * SEQ + qw0) * EMBED + h * HDIM;
  #pragma unroll
  for (int r = 0; r < 16; ++r) {
    int ql = (r & 3) + 8 * (r >> 2) + 4 * hi;
    float inv = dld[wave][ql];
    op[ql * EMBED + l31]      = O0[r] * inv;
    op[ql * EMBED + 32 + l31] = O1[r] * inv;
  }
  #undef STAGE
  #undef LDK
  #undef LDVv
  #undef PROC
  #undef HALF
  #undef COMPUTE
}

extern "C" void kernel_launch(void* const* d_in, const int* in_sizes, int n_in,
                              void* d_out, int out_size, void* d_ws, size_t ws_size,
                              hipStream_t stream) {
  const float* x        = (const float*)d_in[0];
  const float* Wq       = (const float*)d_in[1];
  const float* bq       = (const float*)d_in[2];
  const float* Wk       = (const float*)d_in[3];
  const float* bk       = (const float*)d_in[4];
  const float* Wv       = (const float*)d_in[5];
  const float* bv       = (const float*)d_in[6];
  const float* rel_bias = (const float*)d_in[7];
  float* out = (float*)d_out;

  char* ws = (char*)d_ws;
  unsigned short* Wtb = (unsigned short*)(ws + 16777216);      // 6 MB
  unsigned short* Qb  = (unsigned short*)(ws + 23068672);      // 16 MB
  unsigned short* Kb  = (unsigned short*)(ws + 39845888);      // 16 MB
  unsigned short* Vt  = (unsigned short*)(ws + 56623104);      // 16 MB (total 70 MB)

  transpose_w<<<dim3(32, 32, 3), 256, 0, stream>>>(Wq, Wk, Wv, Wtb);
  qkv_gemm<<<dim3(MTOT / 128, EMBED / 128, 3), 256, 0, stream>>>(x, Wtb, bq, bk, bv, Qb, Kb, Vt);
  attn<<<dim3(SEQ / 128 * BATCH * HEADS), 256, 0, stream>>>(Qb, Kb, Vt, rel_bias, out);
}

// Round 23
// 199.136 us; speedup vs baseline: 1.0924x; 1.0525x over previous
//
#include <hip/hip_runtime.h>

#define EMBED 1024
#define HEADS 16
#define HDIM  64
#define SEQ   2048
#define BATCH 4
#define MTOT  (BATCH*SEQ)

typedef __attribute__((ext_vector_type(8)))  short short8;
typedef __attribute__((ext_vector_type(4)))  float f32x4;
typedef __attribute__((ext_vector_type(16))) float f32x16;

#define GLOAD_LDS16(g, l) \
  __builtin_amdgcn_global_load_lds((const __attribute__((address_space(1))) void*)(g), \
                                   (__attribute__((address_space(3))) void*)(l), 16, 0, 0)

__device__ inline unsigned short f2bf(float f) {
  union { float f; unsigned u; } v; v.f = f;
  unsigned r = v.u + 0x7FFF + ((v.u >> 16) & 1);
  return (unsigned short)(r >> 16);
}

__device__ inline unsigned cvtpk(float lo, float hi) {
  unsigned r;
  asm("v_cvt_pk_bf16_f32 %0, %1, %2" : "=v"(r) : "v"(lo), "v"(hi));
  return r;
}

// raw 2^x — single trans-pipe instr; inputs bounded (|x| < ~8), no edge cases
__device__ inline float vexp2(float x) {
  float r;
  asm("v_exp_f32 %0, %1" : "=v"(r) : "v"(x));
  return r;
}

// v_permlane32_swap_b32 vdst, vsrc — HW semantics (R6/R7 falsification test):
// new vdst[32:63] = old vsrc[0:31]; new vsrc[0:31] = old vdst[32:63].
#define PLSWAP(a, b) asm("v_permlane32_swap_b32 %0, %1" : "+v"(a), "+v"(b))

__device__ inline short8 mk8(unsigned w0, unsigned w1, unsigned w2, unsigned w3) {
  union { unsigned u[4]; short8 s; } x;
  x.u[0] = w0; x.u[1] = w1; x.u[2] = w2; x.u[3] = w3;
  return x.s;
}

// ---------- kernel 1: x fp32 -> bf16 ----------
__global__ void cvt_x(const float* __restrict__ x, unsigned short* __restrict__ xb) {
  int i = (blockIdx.x * blockDim.x + threadIdx.x) * 8;
  f32x4 a = *(const f32x4*)(x + i);
  f32x4 b = *(const f32x4*)(x + i + 4);
  unsigned short o[8];
  o[0]=f2bf(a[0]); o[1]=f2bf(a[1]); o[2]=f2bf(a[2]); o[3]=f2bf(a[3]);
  o[4]=f2bf(b[0]); o[5]=f2bf(b[1]); o[6]=f2bf(b[2]); o[7]=f2bf(b[3]);
  *(short8*)(xb + i) = *(short8*)o;
}

// ---------- kernel 2: W [K][N] fp32 -> Wt [N][K] bf16 (x3) ----------
__global__ void transpose_w(const float* __restrict__ Wq, const float* __restrict__ Wk,
                            const float* __restrict__ Wv, unsigned short* __restrict__ Wtb) {
  __shared__ float tile[32][33];
  int wsel = blockIdx.z;
  const float* W = wsel == 0 ? Wq : (wsel == 1 ? Wk : Wv);
  int k0 = blockIdx.x * 32, n0 = blockIdx.y * 32;
  int tx = threadIdx.x & 31, ty = threadIdx.x >> 5;
  for (int i = 0; i < 4; ++i)
    tile[ty + i*8][tx] = W[(k0 + ty + i*8) * EMBED + n0 + tx];
  __syncthreads();
  unsigned short* o = Wtb + wsel * EMBED * EMBED;
  for (int i = 0; i < 4; ++i)
    o[(n0 + ty + i*8) * EMBED + k0 + tx] = f2bf(tile[tx][ty + i*8]);
}

// ---------- kernel 3: QKV projection GEMM ----------
// Reads bf16 xb (R21 proved fp32-A fused variant costs ~11 us more: 2x A-bytes
// on each of the 24 x-panel re-reads). Q pre-scaled by 0.125*log2(e).
__global__ __launch_bounds__(256)
void qkv_gemm(const unsigned short* __restrict__ xb, const unsigned short* __restrict__ Wtb,
              const float* __restrict__ bq, const float* __restrict__ bk, const float* __restrict__ bv,
              unsigned short* __restrict__ Qb, unsigned short* __restrict__ Kb,
              unsigned short* __restrict__ Vt) {
  __shared__ unsigned short As[128 * 72];
  __shared__ unsigned short Bs[128 * 72];
  int wsel = blockIdx.z;
  int m0 = blockIdx.x * 128, n0 = blockIdx.y * 128;
  int t = threadIdx.x, lane = t & 63, wave = t >> 6;
  int wr = wave >> 1, wc = wave & 1;
  int lr = lane & 15, lg = lane >> 4;
  const unsigned short* Wt = Wtb + wsel * (EMBED * EMBED);
  const float* bias = wsel == 0 ? bq : (wsel == 1 ? bk : bv);

  f32x4 acc[4][4] = {};

  for (int kt = 0; kt < EMBED / 64; ++kt) {
    int k0 = kt * 64;
    for (int i = 0; i < 4; ++i) {
      int c = i * 256 + t;
      int row = c >> 3, col8 = c & 7;
      short8 va = *(const short8*)(xb + (m0 + row) * EMBED + k0 + col8 * 8);
      short8 vb = *(const short8*)(Wt + (n0 + row) * EMBED + k0 + col8 * 8);
      *(short8*)(As + row * 72 + col8 * 8) = va;
      *(short8*)(Bs + row * 72 + col8 * 8) = vb;
    }
    __syncthreads();
    for (int kk = 0; kk < 2; ++kk) {
      short8 af[4], bfr[4];
      for (int mf = 0; mf < 4; ++mf)
        af[mf] = *(const short8*)(As + (wr * 64 + mf * 16 + lr) * 72 + kk * 32 + lg * 8);
      for (int nf = 0; nf < 4; ++nf)
        bfr[nf] = *(const short8*)(Bs + (wc * 64 + nf * 16 + lr) * 72 + kk * 32 + lg * 8);
      for (int mf = 0; mf < 4; ++mf)
        for (int nf = 0; nf < 4; ++nf)
          acc[mf][nf] = __builtin_amdgcn_mfma_f32_16x16x32_bf16(af[mf], bfr[nf], acc[mf][nf], 0, 0, 0);
    }
    __syncthreads();
  }

  const float SCLQ = 0.125f * 1.44269504088896340736f;
  for (int nf = 0; nf < 4; ++nf) {
    int n = n0 + wc * 64 + nf * 16 + lr;
    float bval = bias[n];
    int h = n >> 6, d = n & 63;
    for (int mf = 0; mf < 4; ++mf) {
      for (int r = 0; r < 4; ++r) {
        int m = m0 + wr * 64 + mf * 16 + lg * 4 + r;
        int b = m >> 11, s = m & 2047;
        float oval = acc[mf][nf][r] + bval;
        if (wsel == 0) oval *= SCLQ;   // wave-uniform branch
        unsigned short bfv = f2bf(oval);
        if (wsel == 0)      Qb[((b * HEADS + h) * SEQ + s) * HDIM + d] = bfv;
        else if (wsel == 1) Kb[((b * HEADS + h) * SEQ + s) * HDIM + d] = bfv;
        else                Vt[((b * HEADS + h) * HDIM + d) * SEQ + s] = bfv;
      }
    }
  }
}

// ---------- kernel 4: flash attention, 32x32 MFMA, swapped QK^T ----------
// Best-measured structure (R16: 132.5 us): KVBLK=64, triple-buffer, T1 XCD
// swizzle (FETCH 139->25 MB), counted vmcnt(4) + raw s_barrier, T5 setprio,
// in-register softmax via cvt_pk + permlane32_swap, raw v_exp, no max-shift.
__global__ __launch_bounds__(256)
void attn(const unsigned short* __restrict__ Qb, const unsigned short* __restrict__ Kb,
          const unsigned short* __restrict__ Vt, const float* __restrict__ rel_bias,
          float* __restrict__ out) {
  __shared__ unsigned short KVs[24576];   // K0|K1|K2 | V0|V1|V2, 8 KB per tile
  __shared__ float bias_l[33];
  __shared__ float dld[4][32];
  // T1 swizzle: XCD = bid%8 owns 8 contiguous bh (4 MB K/V = its L2)
  int lid = ((blockIdx.x & 7) << 7) + (blockIdx.x >> 3);
  int bh = lid >> 4;
  int qb = lid & 15;
  int b = bh >> 4, h = bh & 15;
  int t = threadIdx.x, lane = t & 63, wave = t >> 6;
  int l31 = lane & 31, hi = lane >> 5;
  const float LOG2E = 1.44269504088896340736f;
  if (t < 33) bias_l[t] = rel_bias[t * HEADS + h] * LOG2E;

  int qw0 = qb * 128 + wave * 32;                  // this wave's 32 q-rows
  const unsigned short* Qp = Qb + (bh * SEQ + qw0) * HDIM;
  const unsigned short* Kp = Kb + bh * SEQ * HDIM;
  const unsigned short* Vp = Vt + bh * HDIM * SEQ;

  // Q as B-operand fragments: col=q=l31, k(d) = ks*16 + hi*8 + j
  short8 qf[4];
  #pragma unroll
  for (int ks = 0; ks < 4; ++ks)
    qf[ks] = *(const short8*)(Qp + l31 * HDIM + ks * 16 + hi * 8);

  // precomputed per-lane LDS byte offsets, shared by K and V reads:
  // row = rs*32+l31, slot = (ks*2+hi)^(row&7);  off = row*128 + slot*16
  unsigned rbo[2][4];
  #pragma unroll
  for (int rs = 0; rs < 2; ++rs)
    #pragma unroll
    for (int ks = 0; ks < 4; ++ks) {
      int row = rs * 32 + l31;
      rbo[rs][ks] = (unsigned)((row << 7) + ((((ks << 1) | hi) ^ (row & 7)) << 4));
    }
  // byte layout: K buf i at i*8192; V buf i at 24576 + i*8192
  #define LDK(rs, ks, BUF) \
    (*(const short8*)((const char*)KVs + rbo[rs][ks] + (BUF) * 8192))
  #define LDVv(rs, ks, BUF) \
    (*(const short8*)((const char*)KVs + rbo[rs][ks] + 24576 + (BUF) * 8192))

  f32x16 O0 = {}, O1 = {};
  float ls0 = 0.f, ls1 = 0.f;
  int q = qw0 + l31;

  // staging: wave stages rows [wave*16, wave*16+16)
  int srow0 = (wave << 4) + (lane >> 3);
  int sslot = lane & 7;

  #define STAGE(BUF, key0_)                                                          \
    for (int j = 0; j < 2; ++j) {                                                    \
      int srow = srow0 + j * 8;                                                      \
      int cs = sslot ^ (srow & 7);                                                   \
      GLOAD_LDS16(Kp + ((key0_) + srow) * HDIM + cs * 8,                             \
                  (char*)KVs + (BUF) * 8192 + ((((wave << 4) + j * 8) << 6) << 1));  \
      GLOAD_LDS16(Vp + srow * SEQ + (key0_) + cs * 8,                                \
                  (char*)KVs + 24576 + (BUF) * 8192 + ((((wave << 4) + j * 8) << 6) << 1)); \
    }

  #define WAITV4 asm volatile("s_waitcnt vmcnt(4)" ::: "memory");
  #define WAITV0 asm volatile("s_waitcnt vmcnt(0)" ::: "memory");
  #define BAR    __builtin_amdgcn_s_barrier();

  float cbLo, cbHi;

  // softmax + pack + PV for one 32-key subtile held in acc SACC
  #define PROC(SACC, KOFF, BUF)  {                                                   \
    float pv[16];                                                                    \
    int kbase = key0 + (KOFF);                                                       \
    if (kbase >= qw0 + 47) {                                                         \
      _Pragma("unroll") for (int r = 0; r < 16; ++r)                                 \
        pv[r] = vexp2(SACC[r] + cbHi);                                               \
    } else if (kbase <= qw0 - 47) {                                                  \
      _Pragma("unroll") for (int r = 0; r < 16; ++r)                                 \
        pv[r] = vexp2(SACC[r] + cbLo);                                               \
    } else {                                                                         \
      _Pragma("unroll") for (int r = 0; r < 16; ++r) {                               \
        int key = kbase + (r & 3) + 8 * (r >> 2) + 4 * hi;                           \
        int rel = key - q;                                                           \
        rel = rel < -16 ? -16 : (rel > 16 ? 16 : rel);                               \
        pv[r] = vexp2(SACC[r] + bias_l[rel + 16]);                                   \
      }                                                                              \
    }                                                                                \
    ls0 += ((pv[0] + pv[1]) + (pv[2] + pv[3])) + ((pv[4] + pv[5]) + (pv[6] + pv[7]));\
    ls1 += ((pv[8] + pv[9]) + (pv[10] + pv[11])) + ((pv[12] + pv[13]) + (pv[14] + pv[15]));\
    unsigned a0 = cvtpk(pv[0], pv[1]),  a1 = cvtpk(pv[4], pv[5]);   PLSWAP(a0, a1);  \
    unsigned a2 = cvtpk(pv[2], pv[3]),  a3 = cvtpk(pv[6], pv[7]);   PLSWAP(a2, a3);  \
    unsigned b0 = cvtpk(pv[8], pv[9]),  b1 = cvtpk(pv[12], pv[13]); PLSWAP(b0, b1);  \
    unsigned b2 = cvtpk(pv[10], pv[11]), b3 = cvtpk(pv[14], pv[15]); PLSWAP(b2, b3); \
    short8 pa0 = mk8(a0, a2, a1, a3);                                                \
    short8 pa1 = mk8(b0, b2, b1, b3);                                                \
    __builtin_amdgcn_s_setprio(1);                                                   \
    O0 = __builtin_amdgcn_mfma_f32_32x32x16_bf16(pa0, LDVv(0, (KOFF)/16, BUF),     O0, 0, 0, 0); \
    O1 = __builtin_amdgcn_mfma_f32_32x32x16_bf16(pa0, LDVv(1, (KOFF)/16, BUF),     O1, 0, 0, 0); \
    O0 = __builtin_amdgcn_mfma_f32_32x32x16_bf16(pa1, LDVv(0, (KOFF)/16 + 1, BUF), O0, 0, 0, 0); \
    O1 = __builtin_amdgcn_mfma_f32_32x32x16_bf16(pa1, LDVv(1, (KOFF)/16 + 1, BUF), O1, 0, 0, 0); \
    __builtin_amdgcn_s_setprio(0);                                                   \
  }

  // One 32-key half: QK^T chain then its softmax+PV, as a closed region.
  #define HALF(RS, KOFF, BUF)  {                                                     \
    f32x16 s_ = {};                                                                  \
    __builtin_amdgcn_s_setprio(1);                                                   \
    _Pragma("unroll") for (int ks = 0; ks < 4; ++ks)                                 \
      s_ = __builtin_amdgcn_mfma_f32_32x32x16_bf16(LDK(RS, ks, BUF), qf[ks], s_, 0, 0, 0); \
    __builtin_amdgcn_s_setprio(0);                                                   \
    PROC(s_, KOFF, BUF)                                                              \
  }

  #define COMPUTE(BUF, KEY0)  {                                                      \
    int key0 = (KEY0);                                                               \
    HALF(0, 0, BUF)                                                                  \
    HALF(1, 32, BUF)                                                                 \
  }

  // prologue: stage tiles 0,1; wait tile 0; barrier (also covers bias_l)
  STAGE(0, 0)
  STAGE(1, 64)
  WAITV4
  __syncthreads();
  cbLo = bias_l[0]; cbHi = bias_l[32];

  // main: 30 phases in 10 x3-unrolled iterations; tile kb+2 staged each phase
  for (int i = 0; i < 10; ++i) {
    int t3 = i * 3;
    STAGE(2, (t3 + 2) * 64)  COMPUTE(0, t3 * 64)        WAITV4 BAR
    STAGE(0, (t3 + 3) * 64)  COMPUTE(1, (t3 + 1) * 64)  WAITV4 BAR
    STAGE(1, (t3 + 4) * 64)  COMPUTE(2, (t3 + 2) * 64)  WAITV4 BAR
  }
  // tail: tiles 30, 31 (no more staging; drain)
  COMPUTE(0, 30 * 64)
  WAITV0 BAR
  COMPUTE(1, 31 * 64)

  // ---- epilogue: denom per q, normalize, store ----
  float lsum = ls0 + ls1;
  float denom = lsum + __shfl_xor(lsum, 32, 64);
  if (lane < 32) dld[wave][l31] = 1.0f / denom;   // wave-local, wave-synchronous
  float* op = out + (b * SEQ + qw0) * EMBED + h * HDIM;
  #pragma unroll
  for (int r = 0; r < 16; ++r) {
    int ql = (r & 3) + 8 * (r >> 2) + 4 * hi;
    float inv = dld[wave][ql];
    op[ql * EMBED + l31]      = O0[r] * inv;
    op[ql * EMBED + 32 + l31] = O1[r] * inv;
  }
  #undef STAGE
  #undef LDK
  #undef LDVv
  #undef PROC
  #undef HALF
  #undef COMPUTE
}

extern "C" void kernel_launch(void* const* d_in, const int* in_sizes, int n_in,
                              void* d_out, int out_size, void* d_ws, size_t ws_size,
                              hipStream_t stream) {
  const float* x        = (const float*)d_in[0];
  const float* Wq       = (const float*)d_in[1];
  const float* bq       = (const float*)d_in[2];
  const float* Wk       = (const float*)d_in[3];
  const float* bk       = (const float*)d_in[4];
  const float* Wv       = (const float*)d_in[5];
  const float* bv       = (const float*)d_in[6];
  const float* rel_bias = (const float*)d_in[7];
  float* out = (float*)d_out;

  char* ws = (char*)d_ws;
  unsigned short* xb  = (unsigned short*)(ws);                 // 16 MB
  unsigned short* Wtb = (unsigned short*)(ws + 16777216);      // 6 MB
  unsigned short* Qb  = (unsigned short*)(ws + 23068672);      // 16 MB
  unsigned short* Kb  = (unsigned short*)(ws + 39845888);      // 16 MB
  unsigned short* Vt  = (unsigned short*)(ws + 56623104);      // 16 MB (total 70 MB)

  cvt_x<<<MTOT * EMBED / (256 * 8), 256, 0, stream>>>(x, xb);
  transpose_w<<<dim3(32, 32, 3), 256, 0, stream>>>(Wq, Wk, Wv, Wtb);
  qkv_gemm<<<dim3(MTOT / 128, EMBED / 128, 3), 256, 0, stream>>>(xb, Wtb, bq, bk, bv, Qb, Kb, Vt);
  attn<<<dim3(SEQ / 128 * BATCH * HEADS), 256, 0, stream>>>(Qb, Kb, Vt, rel_bias, out);
}

// Round 27
// 198.815 us; speedup vs baseline: 1.0942x; 1.0016x over previous
//
#include <hip/hip_runtime.h>

#define EMBED 1024
#define HEADS 16
#define HDIM  64
#define SEQ   2048
#define BATCH 4
#define MTOT  (BATCH*SEQ)

typedef __attribute__((ext_vector_type(8)))  short short8;
typedef __attribute__((ext_vector_type(4)))  float f32x4;
typedef __attribute__((ext_vector_type(16))) float f32x16;

#define GLOAD_LDS16(g, l) \
  __builtin_amdgcn_global_load_lds((const __attribute__((address_space(1))) void*)(g), \
                                   (__attribute__((address_space(3))) void*)(l), 16, 0, 0)

__device__ inline unsigned short f2bf(float f) {
  union { float f; unsigned u; } v; v.f = f;
  unsigned r = v.u + 0x7FFF + ((v.u >> 16) & 1);
  return (unsigned short)(r >> 16);
}

__device__ inline unsigned cvtpk(float lo, float hi) {
  unsigned r;
  asm("v_cvt_pk_bf16_f32 %0, %1, %2" : "=v"(r) : "v"(lo), "v"(hi));
  return r;
}

// raw 2^x — single trans-pipe instr; inputs bounded (|x| < ~8), no edge cases
__device__ inline float vexp2(float x) {
  float r;
  asm("v_exp_f32 %0, %1" : "=v"(r) : "v"(x));
  return r;
}

// v_permlane32_swap_b32 vdst, vsrc — HW semantics (R6/R7 falsification test):
// new vdst[32:63] = old vsrc[0:31]; new vsrc[0:31] = old vdst[32:63].
#define PLSWAP(a, b) asm("v_permlane32_swap_b32 %0, %1" : "+v"(a), "+v"(b))

__device__ inline short8 mk8(unsigned w0, unsigned w1, unsigned w2, unsigned w3) {
  union { unsigned u[4]; short8 s; } x;
  x.u[0] = w0; x.u[1] = w1; x.u[2] = w2; x.u[3] = w3;
  return x.s;
}

// ---------- kernel 1: x fp32 -> bf16 ----------
__global__ void cvt_x(const float* __restrict__ x, unsigned short* __restrict__ xb) {
  int i = (blockIdx.x * blockDim.x + threadIdx.x) * 8;
  f32x4 a = *(const f32x4*)(x + i);
  f32x4 b = *(const f32x4*)(x + i + 4);
  unsigned short o[8];
  o[0]=f2bf(a[0]); o[1]=f2bf(a[1]); o[2]=f2bf(a[2]); o[3]=f2bf(a[3]);
  o[4]=f2bf(b[0]); o[5]=f2bf(b[1]); o[6]=f2bf(b[2]); o[7]=f2bf(b[3]);
  *(short8*)(xb + i) = *(short8*)o;
}

// ---------- kernel 2: W [K][N] fp32 -> Wt [N][K] bf16 (x3) ----------
__global__ void transpose_w(const float* __restrict__ Wq, const float* __restrict__ Wk,
                            const float* __restrict__ Wv, unsigned short* __restrict__ Wtb) {
  __shared__ float tile[32][33];
  int wsel = blockIdx.z;
  const float* W = wsel == 0 ? Wq : (wsel == 1 ? Wk : Wv);
  int k0 = blockIdx.x * 32, n0 = blockIdx.y * 32;
  int tx = threadIdx.x & 31, ty = threadIdx.x >> 5;
  for (int i = 0; i < 4; ++i)
    tile[ty + i*8][tx] = W[(k0 + ty + i*8) * EMBED + n0 + tx];
  __syncthreads();
  unsigned short* o = Wtb + wsel * EMBED * EMBED;
  for (int i = 0; i < 4; ++i)
    o[(n0 + ty + i*8) * EMBED + k0 + tx] = f2bf(tile[tx][ty + i*8]);
}

// ---------- kernel 3: QKV projection GEMM ----------
// Reads bf16 xb (R21 proved fp32-A fused variant costs ~11 us more: 2x A-bytes
// on each of the 24 x-panel re-reads). Q pre-scaled by 0.125*log2(e).
__global__ __launch_bounds__(256)
void qkv_gemm(const unsigned short* __restrict__ xb, const unsigned short* __restrict__ Wtb,
              const float* __restrict__ bq, const float* __restrict__ bk, const float* __restrict__ bv,
              unsigned short* __restrict__ Qb, unsigned short* __restrict__ Kb,
              unsigned short* __restrict__ Vt) {
  __shared__ unsigned short As[128 * 72];
  __shared__ unsigned short Bs[128 * 72];
  int wsel = blockIdx.z;
  int m0 = blockIdx.x * 128, n0 = blockIdx.y * 128;
  int t = threadIdx.x, lane = t & 63, wave = t >> 6;
  int wr = wave >> 1, wc = wave & 1;
  int lr = lane & 15, lg = lane >> 4;
  const unsigned short* Wt = Wtb + wsel * (EMBED * EMBED);
  const float* bias = wsel == 0 ? bq : (wsel == 1 ? bk : bv);

  f32x4 acc[4][4] = {};

  for (int kt = 0; kt < EMBED / 64; ++kt) {
    int k0 = kt * 64;
    for (int i = 0; i < 4; ++i) {
      int c = i * 256 + t;
      int row = c >> 3, col8 = c & 7;
      short8 va = *(const short8*)(xb + (m0 + row) * EMBED + k0 + col8 * 8);
      short8 vb = *(const short8*)(Wt + (n0 + row) * EMBED + k0 + col8 * 8);
      *(short8*)(As + row * 72 + col8 * 8) = va;
      *(short8*)(Bs + row * 72 + col8 * 8) = vb;
    }
    __syncthreads();
    for (int kk = 0; kk < 2; ++kk) {
      short8 af[4], bfr[4];
      for (int mf = 0; mf < 4; ++mf)
        af[mf] = *(const short8*)(As + (wr * 64 + mf * 16 + lr) * 72 + kk * 32 + lg * 8);
      for (int nf = 0; nf < 4; ++nf)
        bfr[nf] = *(const short8*)(Bs + (wc * 64 + nf * 16 + lr) * 72 + kk * 32 + lg * 8);
      for (int mf = 0; mf < 4; ++mf)
        for (int nf = 0; nf < 4; ++nf)
          acc[mf][nf] = __builtin_amdgcn_mfma_f32_16x16x32_bf16(af[mf], bfr[nf], acc[mf][nf], 0, 0, 0);
    }
    __syncthreads();
  }

  const float SCLQ = 0.125f * 1.44269504088896340736f;
  for (int nf = 0; nf < 4; ++nf) {
    int n = n0 + wc * 64 + nf * 16 + lr;
    float bval = bias[n];
    int h = n >> 6, d = n & 63;
    for (int mf = 0; mf < 4; ++mf) {
      for (int r = 0; r < 4; ++r) {
        int m = m0 + wr * 64 + mf * 16 + lg * 4 + r;
        int b = m >> 11, s = m & 2047;
        float oval = acc[mf][nf][r] + bval;
        if (wsel == 0) oval *= SCLQ;   // wave-uniform branch
        unsigned short bfv = f2bf(oval);
        if (wsel == 0)      Qb[((b * HEADS + h) * SEQ + s) * HDIM + d] = bfv;
        else if (wsel == 1) Kb[((b * HEADS + h) * SEQ + s) * HDIM + d] = bfv;
        else                Vt[((b * HEADS + h) * HDIM + d) * SEQ + s] = bfv;
      }
    }
  }
}

// ---------- kernel 4: flash attention, 32x32 MFMA, swapped QK^T ----------
// Best-measured structure (R16/R23: ~133 us): KVBLK=64, triple-buffer, T1 XCD
// swizzle (FETCH 139->25 MB), counted vmcnt(4) + raw s_barrier, T5 setprio,
// in-register softmax via cvt_pk + permlane32_swap, raw v_exp, no max-shift.
__global__ __launch_bounds__(256)
void attn(const unsigned short* __restrict__ Qb, const unsigned short* __restrict__ Kb,
          const unsigned short* __restrict__ Vt, const float* __restrict__ rel_bias,
          float* __restrict__ out) {
  __shared__ unsigned short KVs[24576];   // K0|K1|K2 | V0|V1|V2, 8 KB per tile
  __shared__ float bias_l[33];
  __shared__ float dld[4][32];
  // T1 swizzle: XCD = bid%8 owns 8 contiguous bh (4 MB K/V = its L2)
  int lid = ((blockIdx.x & 7) << 7) + (blockIdx.x >> 3);
  int bh = lid >> 4;
  int qb = lid & 15;
  int b = bh >> 4, h = bh & 15;
  int t = threadIdx.x, lane = t & 63, wave = t >> 6;
  int l31 = lane & 31, hi = lane >> 5;
  const float LOG2E = 1.44269504088896340736f;
  if (t < 33) bias_l[t] = rel_bias[t * HEADS + h] * LOG2E;

  int qw0 = qb * 128 + wave * 32;                  // this wave's 32 q-rows
  const unsigned short* Qp = Qb + (bh * SEQ + qw0) * HDIM;
  const unsigned short* Kp = Kb + bh * SEQ * HDIM;
  const unsigned short* Vp = Vt + bh * HDIM * SEQ;

  // Q as B-operand fragments: col=q=l31, k(d) = ks*16 + hi*8 + j
  short8 qf[4];
  #pragma unroll
  for (int ks = 0; ks < 4; ++ks)
    qf[ks] = *(const short8*)(Qp + l31 * HDIM + ks * 16 + hi * 8);

  // precomputed per-lane LDS byte offsets, shared by K and V reads:
  // row = rs*32+l31, slot = (ks*2+hi)^(row&7);  off = row*128 + slot*16
  unsigned rbo[2][4];
  #pragma unroll
  for (int rs = 0; rs < 2; ++rs)
    #pragma unroll
    for (int ks = 0; ks < 4; ++ks) {
      int row = rs * 32 + l31;
      rbo[rs][ks] = (unsigned)((row << 7) + ((((ks << 1) | hi) ^ (row & 7)) << 4));
    }
  // byte layout: K buf i at i*8192; V buf i at 24576 + i*8192
  #define LDK(rs, ks, BUF) \
    (*(const short8*)((const char*)KVs + rbo[rs][ks] + (BUF) * 8192))
  #define LDVv(rs, ks, BUF) \
    (*(const short8*)((const char*)KVs + rbo[rs][ks] + 24576 + (BUF) * 8192))

  f32x16 O0 = {}, O1 = {};
  float ls0 = 0.f, ls1 = 0.f;
  int q = qw0 + l31;

  // staging: wave stages rows [wave*16, wave*16+16)
  int srow0 = (wave << 4) + (lane >> 3);
  int sslot = lane & 7;

  #define STAGE(BUF, key0_)                                                          \
    for (int j = 0; j < 2; ++j) {                                                    \
      int srow = srow0 + j * 8;                                                      \
      int cs = sslot ^ (srow & 7);                                                   \
      GLOAD_LDS16(Kp + ((key0_) + srow) * HDIM + cs * 8,                             \
                  (char*)KVs + (BUF) * 8192 + ((((wave << 4) + j * 8) << 6) << 1));  \
      GLOAD_LDS16(Vp + srow * SEQ + (key0_) + cs * 8,                                \
                  (char*)KVs + 24576 + (BUF) * 8192 + ((((wave << 4) + j * 8) << 6) << 1)); \
    }

  #define WAITV4 asm volatile("s_waitcnt vmcnt(4)" ::: "memory");
  #define WAITV0 asm volatile("s_waitcnt vmcnt(0)" ::: "memory");
  #define BAR    __builtin_amdgcn_s_barrier();

  float cbLo, cbHi;

  // softmax + pack + PV for one 32-key subtile held in acc SACC
  #define PROC(SACC, KOFF, BUF)  {                                                   \
    float pv[16];                                                                    \
    int kbase = key0 + (KOFF);                                                       \
    if (kbase >= qw0 + 47) {                                                         \
      _Pragma("unroll") for (int r = 0; r < 16; ++r)                                 \
        pv[r] = vexp2(SACC[r] + cbHi);                                               \
    } else if (kbase <= qw0 - 47) {                                                  \
      _Pragma("unroll") for (int r = 0; r < 16; ++r)                                 \
        pv[r] = vexp2(SACC[r] + cbLo);                                               \
    } else {                                                                         \
      _Pragma("unroll") for (int r = 0; r < 16; ++r) {                               \
        int key = kbase + (r & 3) + 8 * (r >> 2) + 4 * hi;                           \
        int rel = key - q;                                                           \
        rel = rel < -16 ? -16 : (rel > 16 ? 16 : rel);                               \
        pv[r] = vexp2(SACC[r] + bias_l[rel + 16]);                                   \
      }                                                                              \
    }                                                                                \
    ls0 += ((pv[0] + pv[1]) + (pv[2] + pv[3])) + ((pv[4] + pv[5]) + (pv[6] + pv[7]));\
    ls1 += ((pv[8] + pv[9]) + (pv[10] + pv[11])) + ((pv[12] + pv[13]) + (pv[14] + pv[15]));\
    unsigned a0 = cvtpk(pv[0], pv[1]),  a1 = cvtpk(pv[4], pv[5]);   PLSWAP(a0, a1);  \
    unsigned a2 = cvtpk(pv[2], pv[3]),  a3 = cvtpk(pv[6], pv[7]);   PLSWAP(a2, a3);  \
    unsigned b0 = cvtpk(pv[8], pv[9]),  b1 = cvtpk(pv[12], pv[13]); PLSWAP(b0, b1);  \
    unsigned b2 = cvtpk(pv[10], pv[11]), b3 = cvtpk(pv[14], pv[15]); PLSWAP(b2, b3); \
    short8 pa0 = mk8(a0, a2, a1, a3);                                                \
    short8 pa1 = mk8(b0, b2, b1, b3);                                                \
    __builtin_amdgcn_s_setprio(1);                                                   \
    O0 = __builtin_amdgcn_mfma_f32_32x32x16_bf16(pa0, LDVv(0, (KOFF)/16, BUF),     O0, 0, 0, 0); \
    O1 = __builtin_amdgcn_mfma_f32_32x32x16_bf16(pa0, LDVv(1, (KOFF)/16, BUF),     O1, 0, 0, 0); \
    O0 = __builtin_amdgcn_mfma_f32_32x32x16_bf16(pa1, LDVv(0, (KOFF)/16 + 1, BUF), O0, 0, 0, 0); \
    O1 = __builtin_amdgcn_mfma_f32_32x32x16_bf16(pa1, LDVv(1, (KOFF)/16 + 1, BUF), O1, 0, 0, 0); \
    __builtin_amdgcn_s_setprio(0);                                                   \
  }

  // One 32-key half: QK^T chain then its softmax+PV, as a closed region.
  #define HALF(RS, KOFF, BUF)  {                                                     \
    f32x16 s_ = {};                                                                  \
    __builtin_amdgcn_s_setprio(1);                                                   \
    _Pragma("unroll") for (int ks = 0; ks < 4; ++ks)                                 \
      s_ = __builtin_amdgcn_mfma_f32_32x32x16_bf16(LDK(RS, ks, BUF), qf[ks], s_, 0, 0, 0); \
    __builtin_amdgcn_s_setprio(0);                                                   \
    PROC(s_, KOFF, BUF)                                                              \
  }

  #define COMPUTE(BUF, KEY0)  {                                                      \
    int key0 = (KEY0);                                                               \
    HALF(0, 0, BUF)                                                                  \
    HALF(1, 32, BUF)                                                                 \
  }

  // prologue: stage tiles 0,1; wait tile 0; barrier (also covers bias_l)
  STAGE(0, 0)
  STAGE(1, 64)
  WAITV4
  __syncthreads();
  cbLo = bias_l[0]; cbHi = bias_l[32];

  // main: 30 phases in 10 x3-unrolled iterations; tile kb+2 staged each phase
  for (int i = 0; i < 10; ++i) {
    int t3 = i * 3;
    STAGE(2, (t3 + 2) * 64)  COMPUTE(0, t3 * 64)        WAITV4 BAR
    STAGE(0, (t3 + 3) * 64)  COMPUTE(1, (t3 + 1) * 64)  WAITV4 BAR
    STAGE(1, (t3 + 4) * 64)  COMPUTE(2, (t3 + 2) * 64)  WAITV4 BAR
  }
  // tail: tiles 30, 31 (no more staging; drain)
  COMPUTE(0, 30 * 64)
  WAITV0 BAR
  COMPUTE(1, 31 * 64)

  // ---- epilogue: denom per q, normalize, store ----
  float lsum = ls0 + ls1;
  float denom = lsum + __shfl_xor(lsum, 32, 64);
  if (lane < 32) dld[wave][l31] = 1.0f / denom;   // wave-local, wave-synchronous
  float* op = out + (b * SEQ + qw0) * EMBED + h * HDIM;
  #pragma unroll
  for (int r = 0; r < 16; ++r) {
    int ql = (r & 3) + 8 * (r >> 2) + 4 * hi;
    float inv = dld[wave][ql];
    op[ql * EMBED + l31]      = O0[r] * inv;
    op[ql * EMBED + 32 + l31] = O1[r] * inv;
  }
  #undef STAGE
  #undef LDK
  #undef LDVv
  #undef PROC
  #undef HALF
  #undef COMPUTE
}

extern "C" void kernel_launch(void* const* d_in, const int* in_sizes, int n_in,
                              void* d_out, int out_size, void* d_ws, size_t ws_size,
                              hipStream_t stream) {
  const float* x        = (const float*)d_in[0];
  const float* Wq       = (const float*)d_in[1];
  const float* bq       = (const float*)d_in[2];
  const float* Wk       = (const float*)d_in[3];
  const float* bk       = (const float*)d_in[4];
  const float* Wv       = (const float*)d_in[5];
  const float* bv       = (const float*)d_in[6];
  const float* rel_bias = (const float*)d_in[7];
  float* out = (float*)d_out;

  char* ws = (char*)d_ws;
  unsigned short* xb  = (unsigned short*)(ws);                 // 16 MB
  unsigned short* Wtb = (unsigned short*)(ws + 16777216);      // 6 MB
  unsigned short* Qb  = (unsigned short*)(ws + 23068672);      // 16 MB
  unsigned short* Kb  = (unsigned short*)(ws + 39845888);      // 16 MB
  unsigned short* Vt  = (unsigned short*)(ws + 56623104);      // 16 MB (total 70 MB)

  cvt_x<<<MTOT * EMBED / (256 * 8), 256, 0, stream>>>(x, xb);
  transpose_w<<<dim3(32, 32, 3), 256, 0, stream>>>(Wq, Wk, Wv, Wtb);
  qkv_gemm<<<dim3(MTOT / 128, EMBED / 128, 3), 256, 0, stream>>>(xb, Wtb, bq, bk, bv, Qb, Kb, Vt);
  attn<<<dim3(SEQ / 128 * BATCH * HEADS), 256, 0, stream>>>(Qb, Kb, Vt, rel_bias, out);
}